// Round 7
// baseline (272.875 us; speedup 1.0000x reference)
//
#include <hip/hip_runtime.h>
#include <math.h>

#define N_NODES 8192
#define N_EDGES 262144
#define IN_F    256
#define OUT_F   128
#define EDGE_F  16
#define ALPHA_S 0.2f
#define CAPB    128   // bin capacity per row (deg ~ Poisson(32); max ~60)
#define BM      16    // gemm rows per block
#define BK      32    // gemm K chunk
#define NB      1024  // co-resident by construction: 4 blocks/CU x 256 CU
#define GEMM_NB 512
#define EDGE_NB (NB - GEMM_NB)       // 512
#define ROWS_PB (N_NODES / NB)       // 8 rows per block in attn phase

typedef unsigned short u16;
typedef unsigned int   u32;

// round-to-nearest-even f32 -> bf16 bits
__device__ __forceinline__ u16 f2bf(float x) {
  u32 u = __float_as_uint(x);
  return (u16)((u + 0x7fffu + ((u >> 16) & 1u)) >> 16);
}

// software grid barrier: counter pre-zeroed by the memset node each call/replay.
// All NB blocks are co-resident (launch_bounds + LDS budget), so arrive-and-spin
// is deadlock-free; bounded spin turns a miscalc into a visible wrong answer.
__device__ __forceinline__ void grid_barrier(int* __restrict__ bar) {
  __syncthreads();
  if (threadIdx.x == 0) {
    __threadfence();  // release all prior global writes (agent scope)
    __hip_atomic_fetch_add(bar, 1, __ATOMIC_ACQ_REL, __HIP_MEMORY_SCOPE_AGENT);
    int iters = 0;
    while (__hip_atomic_load(bar, __ATOMIC_ACQUIRE, __HIP_MEMORY_SCOPE_AGENT) < NB) {
      __builtin_amdgcn_s_sleep(2);
      if (++iters > (1 << 22)) break;  // safety valve: fail loud, not hang
    }
    __threadfence();  // acquire side
  }
  __syncthreads();
}

__global__ __launch_bounds__(256, 4) void fused_k(
    const float* __restrict__ h, const float* __restrict__ ef,
    const int* __restrict__ src, const int* __restrict__ dst,
    const float* __restrict__ W, const float* __restrict__ W_edge,
    const float* __restrict__ a,
    u16* __restrict__ Whb, float* __restrict__ Wh1, float* __restrict__ Wh2,
    int* __restrict__ counts, int* __restrict__ bar, int2* __restrict__ bins,
    float* __restrict__ out)
{
  __shared__ union {
    struct { float hst[BK][17]; float wsm[BK][OUT_F]; } g;   // 18.5 KiB
    struct { int sdst[4][CAPB + 8]; float sval[4][CAPB]; float sw[4][CAPB + 8]; } t;
    float wc[EDGE_F];
  } sm;
  const int tid = threadIdx.x;
  const int b   = blockIdx.x;

  // ---------------- phase 1: GEMM (b<512) || edge binning (b>=512) ----------------
  if (b < GEMM_NB) {
    const int row0 = b * BM;
    const int rg  = tid >> 5;          // 0..7 -> rows {rg*2, rg*2+1}
    const int cg_ = tid & 31;          // cols cg_*4 .. +3
    const int lrow = tid >> 4;         // A staging: row 0..15
    const int lk2  = tid & 15;         // A staging: float2 slot in K-chunk
    float2 aReg = *(const float2*)(h + (size_t)(row0 + lrow) * IN_F + lk2 * 2);
    float4 wReg[4];
    {
      const float4* w4 = (const float4*)W;
      #pragma unroll
      for (int q = 0; q < 4; ++q) wReg[q] = w4[tid + q * 256];
    }
    float acc[2][4] = {};
    for (int s = 0; s < IN_F / BK; ++s) {
      sm.g.hst[lk2 * 2 + 0][lrow] = aReg.x;   // A^T tile, stride 17: ~2-way write conflict
      sm.g.hst[lk2 * 2 + 1][lrow] = aReg.y;
      float4* ws4 = (float4*)&sm.g.wsm[0][0];
      #pragma unroll
      for (int q = 0; q < 4; ++q) ws4[tid + q * 256] = wReg[q];
      __syncthreads();
      if (s + 1 < IN_F / BK) {                // prefetch next stage during compute
        aReg = *(const float2*)(h + (size_t)(row0 + lrow) * IN_F + (s + 1) * BK + lk2 * 2);
        const float4* w4 = (const float4*)(W + (size_t)(s + 1) * BK * OUT_F);
        #pragma unroll
        for (int q = 0; q < 4; ++q) wReg[q] = w4[tid + q * 256];
      }
      #pragma unroll
      for (int kk = 0; kk < BK; ++kk) {
        const float a0 = sm.g.hst[kk][rg * 2 + 0];     // half-wave broadcast
        const float a1 = sm.g.hst[kk][rg * 2 + 1];
        const float4 bv = *(const float4*)&sm.g.wsm[kk][cg_ * 4];
        const float bvf[4] = {bv.x, bv.y, bv.z, bv.w};
        #pragma unroll
        for (int j = 0; j < 4; ++j) {
          acc[0][j] = fmaf(a0, bvf[j], acc[0][j]);
          acc[1][j] = fmaf(a1, bvf[j], acc[1][j]);
        }
      }
      __syncthreads();
    }
    #pragma unroll
    for (int i = 0; i < 2; ++i) {             // bf16 Wh store
      ushort4 pk;
      pk.x = f2bf(acc[i][0]); pk.y = f2bf(acc[i][1]);
      pk.z = f2bf(acc[i][2]); pk.w = f2bf(acc[i][3]);
      *(ushort4*)(Whb + (size_t)(row0 + rg * 2 + i) * OUT_F + cg_ * 4) = pk;
    }
    float p1[2], p2[2];                       // fused Wh1/Wh2 from f32 accumulators
    #pragma unroll
    for (int i = 0; i < 2; ++i) {
      float s1 = 0.f, s2 = 0.f;
      #pragma unroll
      for (int j = 0; j < 4; ++j) {
        s1 = fmaf(acc[i][j], a[cg_ * 4 + j], s1);
        s2 = fmaf(acc[i][j], a[OUT_F + cg_ * 4 + j], s2);
      }
      p1[i] = s1; p2[i] = s2;
    }
    #pragma unroll
    for (int off = 16; off >= 1; off >>= 1) {
      #pragma unroll
      for (int i = 0; i < 2; ++i) {
        p1[i] += __shfl_xor(p1[i], off);      // reduce across the 32 cg_ lanes
        p2[i] += __shfl_xor(p2[i], off);
      }
    }
    if (cg_ == 0) {
      #pragma unroll
      for (int i = 0; i < 2; ++i) {
        Wh1[row0 + rg * 2 + i] = p1[i];
        Wh2[row0 + rg * 2 + i] = p2[i];
      }
    }
  } else {
    // ---------------- edge binning ----------------
    if (tid < EDGE_F) {
      float s = 0.f;
      #pragma unroll
      for (int j = 0; j < EDGE_F; ++j) s += W_edge[tid * EDGE_F + j] * a[2 * OUT_F + j];
      sm.wc[tid] = s;
    }
    __syncthreads();
    float wcr[EDGE_F];
    #pragma unroll
    for (int j = 0; j < EDGE_F; ++j) wcr[j] = sm.wc[j];
    for (int k = (b - GEMM_NB) * 256 + tid; k < N_EDGES; k += EDGE_NB * 256) {
      const float4* r4 = (const float4*)(ef + (size_t)k * EDGE_F);
      float4 v0 = r4[0], v1 = r4[1], v2 = r4[2], v3 = r4[3];
      float sv = v0.x*wcr[0] + v0.y*wcr[1] + v0.z*wcr[2]  + v0.w*wcr[3]
               + v1.x*wcr[4] + v1.y*wcr[5] + v1.z*wcr[6]  + v1.w*wcr[7]
               + v2.x*wcr[8] + v2.y*wcr[9] + v2.z*wcr[10] + v2.w*wcr[11]
               + v3.x*wcr[12]+ v3.y*wcr[13]+ v3.z*wcr[14] + v3.w*wcr[15];
      int s = src[k], d = dst[k];
      int pos = atomicAdd(&counts[s], 1);     // counts zeroed by memset node
      if (pos < CAPB) bins[(size_t)s * CAPB + pos] = make_int2(d, __float_as_int(sv));
    }
  }

  grid_barrier(bar);

  // ---------------- phase 2: attention, 8 rows/block (2 per wave) ----------------
  const int wsl  = tid >> 6;
  const int lane = tid & 63;
  for (int rr = 0; rr < ROWS_PB / 4; ++rr) {
    const int row = b * ROWS_PB + wsl * 2 + rr;
    int len = counts[row];
    len = len < CAPB ? len : CAPB;
    const int2* bp = bins + (size_t)row * CAPB;
    for (int t = lane; t < len; t += 64) {    // wave-private LDS slice: no block barrier
      int2 e = bp[t];
      sm.t.sdst[wsl][t] = e.x;
      sm.t.sval[wsl][t] = __int_as_float(e.y);
    }
    const float wh1 = Wh1[row];
    float e_loc[CAPB / 64];
    float lmax = -INFINITY;
    int diag_loc = 0;
    #pragma unroll
    for (int u = 0; u < CAPB / 64; ++u) {
      int t = lane + 64 * u;
      float ev = -INFINITY;                   // dup / out-of-range marker
      if (t < len) {
        int d = sm.t.sdst[wsl][t];
        if (d == row) diag_loc = 1;
        bool first = true; float S = 0.f;
        for (int s2 = 0; s2 < len; ++s2) {    // O(len^2)/wave dedupe, len~33
          int d2 = sm.t.sdst[wsl][s2];
          if (d2 == d) {
            if (s2 < t) { first = false; break; }
            S += sm.t.sval[wsl][s2];          // sum duplicates (JAX .add semantics)
          }
        }
        if (first) {
          float x = wh1 + Wh2[d] + S;
          ev = (x > 0.f) ? x : ALPHA_S * x;   // LeakyReLU
        }
      }
      e_loc[u] = ev;
      lmax = fmaxf(lmax, ev);
    }
    const bool has_diag = (__ballot(diag_loc) != 0ull);
    float e_diag = 0.f;
    if (!has_diag) {                          // adj diagonal forced on, no scatter term
      float x = wh1 + Wh2[row];
      e_diag = (x > 0.f) ? x : ALPHA_S * x;
      lmax = fmaxf(lmax, e_diag);
    }
    #pragma unroll
    for (int off = 32; off >= 1; off >>= 1) lmax = fmaxf(lmax, __shfl_xor(lmax, off));
    float lsum = 0.f;
    #pragma unroll
    for (int u = 0; u < CAPB / 64; ++u) {
      int t = lane + 64 * u;
      if (t < len) {
        float w = __expf(e_loc[u] - lmax);    // exp(-inf - m) = 0 for dup slots
        sm.t.sw[wsl][t] = w;
        lsum += w;
      }
    }
    int lenB = len;
    if (!has_diag) {                          // append synthetic diag entry
      float wd = __expf(e_diag - lmax);
      if (lane == 0) { sm.t.sdst[wsl][len] = row; sm.t.sw[wsl][len] = wd; lsum += wd; }
      lenB = len + 1;
    }
    #pragma unroll
    for (int off = 32; off >= 1; off >>= 1) lsum += __shfl_xor(lsum, off);
    const int len4 = (lenB + 3) & ~3;         // pad for branch-free unroll-4
    {
      int t = lenB + lane;
      if (t < len4) { sm.t.sdst[wsl][t] = row; sm.t.sw[wsl][t] = 0.f; }
    }
    // Phase B: lane owns dims {2*lane, 2*lane+1}; one 4B bf16x2 gather per entry
    float acc0 = 0.f, acc1 = 0.f;
    for (int t = 0; t < len4; t += 4) {
      #pragma unroll
      for (int q = 0; q < 4; ++q) {
        float w = sm.t.sw[wsl][t + q];        // LDS broadcast
        u32 v = *(const u32*)(Whb + ((size_t)sm.t.sdst[wsl][t + q] << 7) + 2 * lane);
        acc0 = fmaf(w, __uint_as_float((v & 0xffffu) << 16), acc0);
        acc1 = fmaf(w, __uint_as_float(v & 0xffff0000u), acc1);
      }
    }
    const float inv = 1.f / lsum;
    float o0 = acc0 * inv, o1 = acc1 * inv;
    o0 = (o0 > 0.f) ? o0 : (__expf(o0) - 1.f);  // ELU
    o1 = (o1 > 0.f) ? o1 : (__expf(o1) - 1.f);
    *(float2*)(out + (size_t)row * OUT_F + 2 * lane) = make_float2(o0, o1);
  }
}

extern "C" void kernel_launch(void* const* d_in, const int* in_sizes, int n_in,
                              void* d_out, int out_size, void* d_ws, size_t ws_size,
                              hipStream_t stream) {
  const float* h    = (const float*)d_in[0];
  const float* ef   = (const float*)d_in[1];
  const int*   eidx = (const int*)  d_in[2];
  // d_in[3] = adj — structurally redundant (edges + diagonal), never read: saves 256 MB
  const float* W    = (const float*)d_in[4];
  const float* Wedg = (const float*)d_in[5];
  const float* a    = (const float*)d_in[6];
  float* outp = (float*)d_out;

  char* wsp = (char*)d_ws;
  size_t off = 0;
  auto take = [&](size_t bytes) -> void* {
    void* p = wsp + off;
    off = (off + bytes + 255) & ~(size_t)255;
    return p;
  };
  // counts + bar first: one memset node zeroes both
  int*   counts = (int*)  take((size_t)N_NODES * sizeof(int));             // 32 KiB
  int*   bar    = (int*)  take(256);
  u16*   Whb    = (u16*)  take((size_t)N_NODES * OUT_F * sizeof(u16));     // 2 MiB
  float* Wh1    = (float*)take((size_t)N_NODES * sizeof(float));
  float* Wh2    = (float*)take((size_t)N_NODES * sizeof(float));
  int2*  bins   = (int2*) take((size_t)N_NODES * CAPB * sizeof(int2));     // 8 MiB
  (void)ws_size; (void)in_sizes; (void)n_in; (void)out_size;

  const int* src = eidx;             // edge_indices[0, :]
  const int* dst = eidx + N_EDGES;   // edge_indices[1, :]

  hipMemsetAsync(counts, 0, (size_t)N_NODES * sizeof(int) + 256, stream);
  hipLaunchKernelGGL(fused_k, dim3(NB), dim3(256), 0, stream,
                     h, ef, src, dst, W, Wedg, a, Whb, Wh1, Wh2, counts, bar, bins, outp);
}

// Round 8
// 187.440 us; speedup vs baseline: 1.4558x; 1.4558x over previous
//
#include <hip/hip_runtime.h>
#include <math.h>

#define N_NODES 8192
#define N_EDGES 262144
#define IN_F    256
#define OUT_F   128
#define EDGE_F  16
#define ALPHA_S 0.2f
#define CAPB    128   // bin capacity per row (deg ~ Poisson(32); max ~60)
#define BM      16    // gemm rows per block
#define BK      32    // gemm K chunk
#define NB      1024  // co-resident by construction: 4 blocks/CU x 256 CU
#define GEMM_NB 512
#define EDGE_NB (NB - GEMM_NB)       // 512
#define ROWS_PB (N_NODES / NB)       // 8 rows per block in attn phase

typedef unsigned short u16;
typedef unsigned int   u32;

// round-to-nearest-even f32 -> bf16 bits
__device__ __forceinline__ u16 f2bf(float x) {
  u32 u = __float_as_uint(x);
  return (u16)((u + 0x7fffu + ((u >> 16) & 1u)) >> 16);
}

// Software grid barrier; counter pre-zeroed by the memset node each call/replay.
// R7 lesson: polling one L2 line from 1024 blocks every ~128 cyc collapses the
// fabric (275 us, all pipes idle). Poll at ~4096-cyc granularity instead:
// 1024 pollers -> 0.25 loads/cyc aggregate, negligible. Release ordering via
// ACQ_REL fetch_add (arrive) + ACQUIRE load (exit).
__device__ __forceinline__ void grid_barrier(int* __restrict__ bar) {
  __syncthreads();
  if (threadIdx.x == 0) {
    int arrived = __hip_atomic_fetch_add(bar, 1, __ATOMIC_ACQ_REL, __HIP_MEMORY_SCOPE_AGENT) + 1;
    if (arrived < NB) {
      int iters = 0;
      while (__hip_atomic_load(bar, __ATOMIC_RELAXED, __HIP_MEMORY_SCOPE_AGENT) < NB) {
        __builtin_amdgcn_s_sleep(64);   // ~4096 cycles (~1.7 us) between polls
        if (++iters > 4096) break;      // safety valve: fail loud, not hang
      }
    }
    (void)__hip_atomic_load(bar, __ATOMIC_ACQUIRE, __HIP_MEMORY_SCOPE_AGENT);
  }
  __syncthreads();
}

__global__ __launch_bounds__(256, 4) void fused_k(
    const float* __restrict__ h, const float* __restrict__ ef,
    const int* __restrict__ src, const int* __restrict__ dst,
    const float* __restrict__ W, const float* __restrict__ W_edge,
    const float* __restrict__ a,
    u16* __restrict__ Whb, float* __restrict__ Wh1, float* __restrict__ Wh2,
    int* __restrict__ counts, int* __restrict__ bar, int2* __restrict__ bins,
    float* __restrict__ out)
{
  __shared__ union {
    struct { float hst[BK][17]; float wsm[BK][OUT_F]; } g;   // 18.5 KiB
    struct { int sdst[4][CAPB + 8]; float sval[4][CAPB]; float sw[4][CAPB + 8]; } t;
    float wc[EDGE_F];
  } sm;
  const int tid = threadIdx.x;
  const int b   = blockIdx.x;

  // ---------------- phase 1: GEMM (b<512) || edge binning (b>=512) ----------------
  if (b < GEMM_NB) {
    const int row0 = b * BM;
    const int rg  = tid >> 5;          // 0..7 -> rows {rg*2, rg*2+1}
    const int cg_ = tid & 31;          // cols cg_*4 .. +3
    const int lrow = tid >> 4;         // A staging: row 0..15
    const int lk2  = tid & 15;         // A staging: float2 slot in K-chunk
    float2 aReg = *(const float2*)(h + (size_t)(row0 + lrow) * IN_F + lk2 * 2);
    float4 wReg[4];
    {
      const float4* w4 = (const float4*)W;
      #pragma unroll
      for (int q = 0; q < 4; ++q) wReg[q] = w4[tid + q * 256];
    }
    float acc[2][4] = {};
    for (int s = 0; s < IN_F / BK; ++s) {
      sm.g.hst[lk2 * 2 + 0][lrow] = aReg.x;   // A^T tile, stride 17: ~2-way write conflict
      sm.g.hst[lk2 * 2 + 1][lrow] = aReg.y;
      float4* ws4 = (float4*)&sm.g.wsm[0][0];
      #pragma unroll
      for (int q = 0; q < 4; ++q) ws4[tid + q * 256] = wReg[q];
      __syncthreads();
      if (s + 1 < IN_F / BK) {                // prefetch next stage during compute
        aReg = *(const float2*)(h + (size_t)(row0 + lrow) * IN_F + (s + 1) * BK + lk2 * 2);
        const float4* w4 = (const float4*)(W + (size_t)(s + 1) * BK * OUT_F);
        #pragma unroll
        for (int q = 0; q < 4; ++q) wReg[q] = w4[tid + q * 256];
      }
      #pragma unroll
      for (int kk = 0; kk < BK; ++kk) {
        const float a0 = sm.g.hst[kk][rg * 2 + 0];     // half-wave broadcast
        const float a1 = sm.g.hst[kk][rg * 2 + 1];
        const float4 bv = *(const float4*)&sm.g.wsm[kk][cg_ * 4];
        const float bvf[4] = {bv.x, bv.y, bv.z, bv.w};
        #pragma unroll
        for (int j = 0; j < 4; ++j) {
          acc[0][j] = fmaf(a0, bvf[j], acc[0][j]);
          acc[1][j] = fmaf(a1, bvf[j], acc[1][j]);
        }
      }
      __syncthreads();
    }
    #pragma unroll
    for (int i = 0; i < 2; ++i) {             // bf16 Wh store
      ushort4 pk;
      pk.x = f2bf(acc[i][0]); pk.y = f2bf(acc[i][1]);
      pk.z = f2bf(acc[i][2]); pk.w = f2bf(acc[i][3]);
      *(ushort4*)(Whb + (size_t)(row0 + rg * 2 + i) * OUT_F + cg_ * 4) = pk;
    }
    float p1[2], p2[2];                       // fused Wh1/Wh2 from f32 accumulators
    #pragma unroll
    for (int i = 0; i < 2; ++i) {
      float s1 = 0.f, s2 = 0.f;
      #pragma unroll
      for (int j = 0; j < 4; ++j) {
        s1 = fmaf(acc[i][j], a[cg_ * 4 + j], s1);
        s2 = fmaf(acc[i][j], a[OUT_F + cg_ * 4 + j], s2);
      }
      p1[i] = s1; p2[i] = s2;
    }
    #pragma unroll
    for (int off = 16; off >= 1; off >>= 1) {
      #pragma unroll
      for (int i = 0; i < 2; ++i) {
        p1[i] += __shfl_xor(p1[i], off);      // reduce across the 32 cg_ lanes
        p2[i] += __shfl_xor(p2[i], off);
      }
    }
    if (cg_ == 0) {
      #pragma unroll
      for (int i = 0; i < 2; ++i) {
        Wh1[row0 + rg * 2 + i] = p1[i];
        Wh2[row0 + rg * 2 + i] = p2[i];
      }
    }
  } else {
    // ---------------- edge binning ----------------
    if (tid < EDGE_F) {
      float s = 0.f;
      #pragma unroll
      for (int j = 0; j < EDGE_F; ++j) s += W_edge[tid * EDGE_F + j] * a[2 * OUT_F + j];
      sm.wc[tid] = s;
    }
    __syncthreads();
    float wcr[EDGE_F];
    #pragma unroll
    for (int j = 0; j < EDGE_F; ++j) wcr[j] = sm.wc[j];
    for (int k = (b - GEMM_NB) * 256 + tid; k < N_EDGES; k += EDGE_NB * 256) {
      const float4* r4 = (const float4*)(ef + (size_t)k * EDGE_F);
      float4 v0 = r4[0], v1 = r4[1], v2 = r4[2], v3 = r4[3];
      float sv = v0.x*wcr[0] + v0.y*wcr[1] + v0.z*wcr[2]  + v0.w*wcr[3]
               + v1.x*wcr[4] + v1.y*wcr[5] + v1.z*wcr[6]  + v1.w*wcr[7]
               + v2.x*wcr[8] + v2.y*wcr[9] + v2.z*wcr[10] + v2.w*wcr[11]
               + v3.x*wcr[12]+ v3.y*wcr[13]+ v3.z*wcr[14] + v3.w*wcr[15];
      int s = src[k], d = dst[k];
      int pos = atomicAdd(&counts[s], 1);     // counts zeroed by memset node
      if (pos < CAPB) bins[(size_t)s * CAPB + pos] = make_int2(d, __float_as_int(sv));
    }
  }

  grid_barrier(bar);

  // ---------------- phase 2: attention, 8 rows/block (2 per wave) ----------------
  const int wsl  = tid >> 6;
  const int lane = tid & 63;
  for (int rr = 0; rr < ROWS_PB / 4; ++rr) {
    const int row = b * ROWS_PB + wsl * 2 + rr;
    int len = counts[row];
    len = len < CAPB ? len : CAPB;
    const int2* bp = bins + (size_t)row * CAPB;
    for (int t = lane; t < len; t += 64) {    // wave-private LDS slice: no block barrier
      int2 e = bp[t];
      sm.t.sdst[wsl][t] = e.x;
      sm.t.sval[wsl][t] = __int_as_float(e.y);
    }
    const float wh1 = Wh1[row];
    float e_loc[CAPB / 64];
    float lmax = -INFINITY;
    int diag_loc = 0;
    #pragma unroll
    for (int u = 0; u < CAPB / 64; ++u) {
      int t = lane + 64 * u;
      float ev = -INFINITY;                   // dup / out-of-range marker
      if (t < len) {
        int d = sm.t.sdst[wsl][t];
        if (d == row) diag_loc = 1;
        bool first = true; float S = 0.f;
        for (int s2 = 0; s2 < len; ++s2) {    // O(len^2)/wave dedupe, len~33
          int d2 = sm.t.sdst[wsl][s2];
          if (d2 == d) {
            if (s2 < t) { first = false; break; }
            S += sm.t.sval[wsl][s2];          // sum duplicates (JAX .add semantics)
          }
        }
        if (first) {
          float x = wh1 + Wh2[d] + S;
          ev = (x > 0.f) ? x : ALPHA_S * x;   // LeakyReLU
        }
      }
      e_loc[u] = ev;
      lmax = fmaxf(lmax, ev);
    }
    const bool has_diag = (__ballot(diag_loc) != 0ull);
    float e_diag = 0.f;
    if (!has_diag) {                          // adj diagonal forced on, no scatter term
      float x = wh1 + Wh2[row];
      e_diag = (x > 0.f) ? x : ALPHA_S * x;
      lmax = fmaxf(lmax, e_diag);
    }
    #pragma unroll
    for (int off = 32; off >= 1; off >>= 1) lmax = fmaxf(lmax, __shfl_xor(lmax, off));
    float lsum = 0.f;
    #pragma unroll
    for (int u = 0; u < CAPB / 64; ++u) {
      int t = lane + 64 * u;
      if (t < len) {
        float w = __expf(e_loc[u] - lmax);    // exp(-inf - m) = 0 for dup slots
        sm.t.sw[wsl][t] = w;
        lsum += w;
      }
    }
    int lenB = len;
    if (!has_diag) {                          // append synthetic diag entry
      float wd = __expf(e_diag - lmax);
      if (lane == 0) { sm.t.sdst[wsl][len] = row; sm.t.sw[wsl][len] = wd; lsum += wd; }
      lenB = len + 1;
    }
    #pragma unroll
    for (int off = 32; off >= 1; off >>= 1) lsum += __shfl_xor(lsum, off);
    const int len4 = (lenB + 3) & ~3;         // pad for branch-free unroll-4
    {
      int t = lenB + lane;
      if (t < len4) { sm.t.sdst[wsl][t] = row; sm.t.sw[wsl][t] = 0.f; }
    }
    // Phase B: lane owns dims {2*lane, 2*lane+1}; one 4B bf16x2 gather per entry
    float acc0 = 0.f, acc1 = 0.f;
    for (int t = 0; t < len4; t += 4) {
      #pragma unroll
      for (int q = 0; q < 4; ++q) {
        float w = sm.t.sw[wsl][t + q];        // LDS broadcast
        u32 v = *(const u32*)(Whb + ((size_t)sm.t.sdst[wsl][t + q] << 7) + 2 * lane);
        acc0 = fmaf(w, __uint_as_float((v & 0xffffu) << 16), acc0);
        acc1 = fmaf(w, __uint_as_float(v & 0xffff0000u), acc1);
      }
    }
    const float inv = 1.f / lsum;
    float o0 = acc0 * inv, o1 = acc1 * inv;
    o0 = (o0 > 0.f) ? o0 : (__expf(o0) - 1.f);  // ELU
    o1 = (o1 > 0.f) ? o1 : (__expf(o1) - 1.f);
    *(float2*)(out + (size_t)row * OUT_F + 2 * lane) = make_float2(o0, o1);
  }
}

extern "C" void kernel_launch(void* const* d_in, const int* in_sizes, int n_in,
                              void* d_out, int out_size, void* d_ws, size_t ws_size,
                              hipStream_t stream) {
  const float* h    = (const float*)d_in[0];
  const float* ef   = (const float*)d_in[1];
  const int*   eidx = (const int*)  d_in[2];
  // d_in[3] = adj — structurally redundant (edges + diagonal), never read: saves 256 MB
  const float* W    = (const float*)d_in[4];
  const float* Wedg = (const float*)d_in[5];
  const float* a    = (const float*)d_in[6];
  float* outp = (float*)d_out;

  char* wsp = (char*)d_ws;
  size_t off = 0;
  auto take = [&](size_t bytes) -> void* {
    void* p = wsp + off;
    off = (off + bytes + 255) & ~(size_t)255;
    return p;
  };
  // counts + bar first: one memset node zeroes both
  int*   counts = (int*)  take((size_t)N_NODES * sizeof(int));             // 32 KiB
  int*   bar    = (int*)  take(256);
  u16*   Whb    = (u16*)  take((size_t)N_NODES * OUT_F * sizeof(u16));     // 2 MiB
  float* Wh1    = (float*)take((size_t)N_NODES * sizeof(float));
  float* Wh2    = (float*)take((size_t)N_NODES * sizeof(float));
  int2*  bins   = (int2*) take((size_t)N_NODES * CAPB * sizeof(int2));     // 8 MiB
  (void)ws_size; (void)in_sizes; (void)n_in; (void)out_size;

  const int* src = eidx;             // edge_indices[0, :]
  const int* dst = eidx + N_EDGES;   // edge_indices[1, :]

  hipMemsetAsync(counts, 0, (size_t)N_NODES * sizeof(int) + 256, stream);
  hipLaunchKernelGGL(fused_k, dim3(NB), dim3(256), 0, stream,
                     h, ef, src, dst, W, Wedg, a, Whb, Wh1, Wh2, counts, bar, bins, outp);
}

// Round 9
// 83.657 us; speedup vs baseline: 3.2618x; 2.2406x over previous
//
#include <hip/hip_runtime.h>
#include <math.h>

#define N_NODES 8192
#define N_EDGES 262144
#define IN_F    256
#define OUT_F   128
#define EDGE_F  16
#define ALPHA_S 0.2f
#define CAPB    128   // bin capacity per row (deg ~ Poisson(32); max ~60)
#define BM      16    // gemm rows per block
#define BK      32    // gemm K chunk
#define P1_NB   1024
#define GEMM_NB 512
#define EDGE_NB (P1_NB - GEMM_NB)    // 512

typedef unsigned short u16;
typedef unsigned int   u32;

// round-to-nearest-even f32 -> bf16 bits
__device__ __forceinline__ u16 f2bf(float x) {
  u32 u = __float_as_uint(x);
  return (u16)((u + 0x7fffu + ((u >> 16) & 1u)) >> 16);
}

// ---------------- phase 1: GEMM (b<512) || edge binning (b>=512) ----------------
__global__ __launch_bounds__(256) void phase1_k(
    const float* __restrict__ h, const float* __restrict__ ef,
    const int* __restrict__ src, const int* __restrict__ dst,
    const float* __restrict__ W, const float* __restrict__ W_edge,
    const float* __restrict__ a,
    u16* __restrict__ Whb, float* __restrict__ Wh1, float* __restrict__ Wh2,
    int* __restrict__ counts, int2* __restrict__ bins)
{
  __shared__ union {
    struct { float hst[BK][17]; float wsm[BK][OUT_F]; } g;   // 18.5 KiB
    float wc[EDGE_F];
  } sm;
  const int tid = threadIdx.x;
  const int b   = blockIdx.x;

  if (b < GEMM_NB) {
    const int row0 = b * BM;
    const int rg  = tid >> 5;          // 0..7 -> rows {rg*2, rg*2+1}
    const int cg_ = tid & 31;          // cols cg_*4 .. +3
    const int lrow = tid >> 4;         // A staging: row 0..15
    const int lk2  = tid & 15;         // A staging: float2 slot in K-chunk
    float2 aReg = *(const float2*)(h + (size_t)(row0 + lrow) * IN_F + lk2 * 2);
    float4 wReg[4];
    {
      const float4* w4 = (const float4*)W;
      #pragma unroll
      for (int q = 0; q < 4; ++q) wReg[q] = w4[tid + q * 256];
    }
    float acc[2][4] = {};
    for (int s = 0; s < IN_F / BK; ++s) {
      sm.g.hst[lk2 * 2 + 0][lrow] = aReg.x;   // A^T tile, stride 17
      sm.g.hst[lk2 * 2 + 1][lrow] = aReg.y;
      float4* ws4 = (float4*)&sm.g.wsm[0][0];
      #pragma unroll
      for (int q = 0; q < 4; ++q) ws4[tid + q * 256] = wReg[q];
      __syncthreads();
      if (s + 1 < IN_F / BK) {                // prefetch next stage during compute
        aReg = *(const float2*)(h + (size_t)(row0 + lrow) * IN_F + (s + 1) * BK + lk2 * 2);
        const float4* w4 = (const float4*)(W + (size_t)(s + 1) * BK * OUT_F);
        #pragma unroll
        for (int q = 0; q < 4; ++q) wReg[q] = w4[tid + q * 256];
      }
      #pragma unroll
      for (int kk = 0; kk < BK; ++kk) {
        const float a0 = sm.g.hst[kk][rg * 2 + 0];     // broadcast
        const float a1 = sm.g.hst[kk][rg * 2 + 1];
        const float4 bv = *(const float4*)&sm.g.wsm[kk][cg_ * 4];
        const float bvf[4] = {bv.x, bv.y, bv.z, bv.w};
        #pragma unroll
        for (int j = 0; j < 4; ++j) {
          acc[0][j] = fmaf(a0, bvf[j], acc[0][j]);
          acc[1][j] = fmaf(a1, bvf[j], acc[1][j]);
        }
      }
      __syncthreads();
    }
    #pragma unroll
    for (int i = 0; i < 2; ++i) {             // bf16 Wh store
      ushort4 pk;
      pk.x = f2bf(acc[i][0]); pk.y = f2bf(acc[i][1]);
      pk.z = f2bf(acc[i][2]); pk.w = f2bf(acc[i][3]);
      *(ushort4*)(Whb + (size_t)(row0 + rg * 2 + i) * OUT_F + cg_ * 4) = pk;
    }
    float p1[2], p2[2];                       // fused Wh1/Wh2 from f32 accumulators
    #pragma unroll
    for (int i = 0; i < 2; ++i) {
      float s1 = 0.f, s2 = 0.f;
      #pragma unroll
      for (int j = 0; j < 4; ++j) {
        s1 = fmaf(acc[i][j], a[cg_ * 4 + j], s1);
        s2 = fmaf(acc[i][j], a[OUT_F + cg_ * 4 + j], s2);
      }
      p1[i] = s1; p2[i] = s2;
    }
    #pragma unroll
    for (int off = 16; off >= 1; off >>= 1) {
      #pragma unroll
      for (int i = 0; i < 2; ++i) {
        p1[i] += __shfl_xor(p1[i], off);      // reduce across the 32 cg_ lanes
        p2[i] += __shfl_xor(p2[i], off);
      }
    }
    if (cg_ == 0) {
      #pragma unroll
      for (int i = 0; i < 2; ++i) {
        Wh1[row0 + rg * 2 + i] = p1[i];
        Wh2[row0 + rg * 2 + i] = p2[i];
      }
    }
  } else {
    // ---------------- edge binning ----------------
    if (tid < EDGE_F) {
      float s = 0.f;
      #pragma unroll
      for (int j = 0; j < EDGE_F; ++j) s += W_edge[tid * EDGE_F + j] * a[2 * OUT_F + j];
      sm.wc[tid] = s;
    }
    __syncthreads();
    float wcr[EDGE_F];
    #pragma unroll
    for (int j = 0; j < EDGE_F; ++j) wcr[j] = sm.wc[j];
    for (int k = (b - GEMM_NB) * 256 + tid; k < N_EDGES; k += EDGE_NB * 256) {
      const float4* r4 = (const float4*)(ef + (size_t)k * EDGE_F);
      float4 v0 = r4[0], v1 = r4[1], v2 = r4[2], v3 = r4[3];
      float sv = v0.x*wcr[0] + v0.y*wcr[1] + v0.z*wcr[2]  + v0.w*wcr[3]
               + v1.x*wcr[4] + v1.y*wcr[5] + v1.z*wcr[6]  + v1.w*wcr[7]
               + v2.x*wcr[8] + v2.y*wcr[9] + v2.z*wcr[10] + v2.w*wcr[11]
               + v3.x*wcr[12]+ v3.y*wcr[13]+ v3.z*wcr[14] + v3.w*wcr[15];
      int s = src[k], d = dst[k];
      int pos = atomicAdd(&counts[s], 1);     // counts zeroed by memset node
      if (pos < CAPB) bins[(size_t)s * CAPB + pos] = make_int2(d, __float_as_int(sv));
    }
  }
}

// ---------------- phase 2: attention, one wave per row ----------------
__global__ __launch_bounds__(256) void phase2_k(
    const u16* __restrict__ Whb, const float* __restrict__ Wh1, const float* __restrict__ Wh2,
    const int* __restrict__ counts, const int2* __restrict__ bins, float* __restrict__ out)
{
  __shared__ int   sdst[4][CAPB + 8];
  __shared__ float sval[4][CAPB];
  __shared__ float sw[4][CAPB + 8];
  const int wsl  = threadIdx.x >> 6;
  const int lane = threadIdx.x & 63;
  const int row  = blockIdx.x * 4 + wsl;
  int len = counts[row];
  len = len < CAPB ? len : CAPB;
  const int2* bp = bins + (size_t)row * CAPB;
  for (int t = lane; t < len; t += 64) {      // wave-private LDS slice: no block barrier
    int2 e = bp[t];
    sdst[wsl][t] = e.x;
    sval[wsl][t] = __int_as_float(e.y);
  }
  const float wh1 = Wh1[row];
  float e_loc[CAPB / 64];
  float lmax = -INFINITY;
  int diag_loc = 0;
  #pragma unroll
  for (int u = 0; u < CAPB / 64; ++u) {
    int t = lane + 64 * u;
    float ev = -INFINITY;                     // dup / out-of-range marker
    if (t < len) {
      int d = sdst[wsl][t];
      if (d == row) diag_loc = 1;
      bool first = true; float S = 0.f;
      for (int s2 = 0; s2 < len; ++s2) {      // O(len^2)/wave dedupe, len~33
        int d2 = sdst[wsl][s2];
        if (d2 == d) {
          if (s2 < t) { first = false; break; }
          S += sval[wsl][s2];                 // sum duplicates (JAX .add semantics)
        }
      }
      if (first) {
        float x = wh1 + Wh2[d] + S;
        ev = (x > 0.f) ? x : ALPHA_S * x;     // LeakyReLU
      }
    }
    e_loc[u] = ev;
    lmax = fmaxf(lmax, ev);
  }
  const bool has_diag = (__ballot(diag_loc) != 0ull);
  float e_diag = 0.f;
  if (!has_diag) {                            // adj diagonal forced on, no scatter term
    float x = wh1 + Wh2[row];
    e_diag = (x > 0.f) ? x : ALPHA_S * x;
    lmax = fmaxf(lmax, e_diag);
  }
  #pragma unroll
  for (int off = 32; off >= 1; off >>= 1) lmax = fmaxf(lmax, __shfl_xor(lmax, off));
  float lsum = 0.f;
  #pragma unroll
  for (int u = 0; u < CAPB / 64; ++u) {
    int t = lane + 64 * u;
    if (t < len) {
      float w = __expf(e_loc[u] - lmax);      // exp(-inf - m) = 0 for dup slots
      sw[wsl][t] = w;
      lsum += w;
    }
  }
  int lenB = len;
  if (!has_diag) {                            // append synthetic diag entry
    float wd = __expf(e_diag - lmax);
    if (lane == 0) { sdst[wsl][len] = row; sw[wsl][len] = wd; lsum += wd; }
    lenB = len + 1;
  }
  #pragma unroll
  for (int off = 32; off >= 1; off >>= 1) lsum += __shfl_xor(lsum, off);
  const int len4 = (lenB + 3) & ~3;           // pad for branch-free unroll-4
  {
    int t = lenB + lane;
    if (t < len4) { sdst[wsl][t] = row; sw[wsl][t] = 0.f; }
  }
  // Phase B: lane owns dims {2*lane, 2*lane+1}; one 4B bf16x2 gather per entry
  float acc0 = 0.f, acc1 = 0.f;
  for (int t = 0; t < len4; t += 4) {
    #pragma unroll
    for (int q = 0; q < 4; ++q) {
      float w = sw[wsl][t + q];               // LDS broadcast
      u32 v = *(const u32*)(Whb + ((size_t)sdst[wsl][t + q] << 7) + 2 * lane);
      acc0 = fmaf(w, __uint_as_float((v & 0xffffu) << 16), acc0);
      acc1 = fmaf(w, __uint_as_float(v & 0xffff0000u), acc1);
    }
  }
  const float inv = 1.f / lsum;
  float o0 = acc0 * inv, o1 = acc1 * inv;
  o0 = (o0 > 0.f) ? o0 : (__expf(o0) - 1.f);  // ELU
  o1 = (o1 > 0.f) ? o1 : (__expf(o1) - 1.f);
  *(float2*)(out + (size_t)row * OUT_F + 2 * lane) = make_float2(o0, o1);
}

extern "C" void kernel_launch(void* const* d_in, const int* in_sizes, int n_in,
                              void* d_out, int out_size, void* d_ws, size_t ws_size,
                              hipStream_t stream) {
  const float* h    = (const float*)d_in[0];
  const float* ef   = (const float*)d_in[1];
  const int*   eidx = (const int*)  d_in[2];
  // d_in[3] = adj — structurally redundant (edges + diagonal), never read: saves 256 MB
  const float* W    = (const float*)d_in[4];
  const float* Wedg = (const float*)d_in[5];
  const float* a    = (const float*)d_in[6];
  float* outp = (float*)d_out;

  char* wsp = (char*)d_ws;
  size_t off = 0;
  auto take = [&](size_t bytes) -> void* {
    void* p = wsp + off;
    off = (off + bytes + 255) & ~(size_t)255;
    return p;
  };
  int*   counts = (int*)  take((size_t)N_NODES * sizeof(int));             // 32 KiB
  u16*   Whb    = (u16*)  take((size_t)N_NODES * OUT_F * sizeof(u16));     // 2 MiB
  float* Wh1    = (float*)take((size_t)N_NODES * sizeof(float));
  float* Wh2    = (float*)take((size_t)N_NODES * sizeof(float));
  int2*  bins   = (int2*) take((size_t)N_NODES * CAPB * sizeof(int2));     // 8 MiB
  (void)ws_size; (void)in_sizes; (void)n_in; (void)out_size;

  const int* src = eidx;             // edge_indices[0, :]
  const int* dst = eidx + N_EDGES;   // edge_indices[1, :]

  hipMemsetAsync(counts, 0, (size_t)N_NODES * sizeof(int), stream);
  hipLaunchKernelGGL(phase1_k, dim3(P1_NB), dim3(256), 0, stream,
                     h, ef, src, dst, W, Wedg, a, Whb, Wh1, Wh2, counts, bins);
  hipLaunchKernelGGL(phase2_k, dim3(N_NODES / 4), dim3(256), 0, stream,
                     Whb, Wh1, Wh2, counts, bins, outp);
}

// Round 10
// 50.395 us; speedup vs baseline: 5.4147x; 1.6600x over previous
//
#include <hip/hip_runtime.h>
#include <math.h>

#define N_NODES 8192
#define N_EDGES 262144
#define IN_F    256
#define OUT_F   128
#define EDGE_F  16
#define ALPHA_S 0.2f
#define CAPB    128   // bin capacity per row (deg ~ Poisson(32); max ~60)
#define BM      32    // gemm tile rows per block
#define KH      128   // K half staged per round
#define LDK     136   // padded LDS row (bf16 elems): 272 B, 16B-aligned, ~2-way banks
#define P1_NB   1024
#define GEMM_NB 256
#define EDGE_NB (P1_NB - GEMM_NB)    // 768

typedef unsigned short u16;
typedef unsigned int   u32;
typedef short  bf16x8 __attribute__((ext_vector_type(8)));
typedef float  f32x4  __attribute__((ext_vector_type(4)));

// round-to-nearest-even f32 -> bf16 bits
__device__ __forceinline__ u16 f2bf(float x) {
  u32 u = __float_as_uint(x);
  return (u16)((u + 0x7fffu + ((u >> 16) & 1u)) >> 16);
}

// ---------------- init: zero counts + W^T -> bf16 (replaces memset node) ----------------
__global__ __launch_bounds__(256) void init_k(const float* __restrict__ W,
                                              u16* __restrict__ WbT,
                                              int* __restrict__ counts) {
  const int idx = blockIdx.x * 256 + threadIdx.x;     // 128 blocks x 256 = 32768
  if (idx < N_NODES) counts[idx] = 0;
  const int n = idx & 127, k = idx >> 7;              // read W[k][n..] coalesced
  WbT[(size_t)n * IN_F + k] = f2bf(W[(size_t)k * OUT_F + n]);
}

// ---------------- phase 1: MFMA GEMM (b<256) || edge binning (b>=256) ----------------
__global__ __launch_bounds__(256) void phase1_k(
    const float* __restrict__ h, const float* __restrict__ ef,
    const int* __restrict__ src, const int* __restrict__ dst,
    const u16* __restrict__ WbT, const float* __restrict__ W_edge,
    const float* __restrict__ a,
    u16* __restrict__ Whb, float* __restrict__ Wh1, float* __restrict__ Wh2,
    int* __restrict__ counts, int2* __restrict__ bins)
{
  __shared__ union {
    struct {
      u16 Alds[BM][LDK];       // 8.5 KiB  (h tile, bf16)
      u16 Wlds[OUT_F][LDK];    // 34 KiB   (W^T tile, bf16)
      float whp[2][BM];        // Wh1/Wh2 reduction
    } g;                        // ~42.9 KiB -> 3 blocks/CU
    float wc[EDGE_F];
  } sm;
  const int tid = threadIdx.x;
  const int b   = blockIdx.x;

  if (b < GEMM_NB) {
    const int row0 = b * BM;
    const int w   = tid >> 6;         // wave 0..3 -> n-tiles {2w, 2w+1}
    const int l   = tid & 63;
    const int r15 = l & 15;
    const int kg  = l >> 4;           // 0..3
    if (tid < 64) sm.g.whp[tid >> 5][tid & 31] = 0.f;

    f32x4 acc[2][2] = {};             // [m-tile][n-tile]

    for (int s = 0; s < IN_F / KH; ++s) {   // 2 K-halves
      // stage A: 32 rows x 128 k, bf16-convert. thread: r=tid>>3, kc=(tid&7)*16
      {
        const int r = tid >> 3, kc = (tid & 7) * 16;
        const float4* hp = (const float4*)(h + (size_t)(row0 + r) * IN_F + s * KH + kc);
        float4 f0 = hp[0], f1 = hp[1], f2 = hp[2], f3 = hp[3];
        uint4 p0, p1;
        p0.x = f2bf(f0.x) | ((u32)f2bf(f0.y) << 16);
        p0.y = f2bf(f0.z) | ((u32)f2bf(f0.w) << 16);
        p0.z = f2bf(f1.x) | ((u32)f2bf(f1.y) << 16);
        p0.w = f2bf(f1.z) | ((u32)f2bf(f1.w) << 16);
        p1.x = f2bf(f2.x) | ((u32)f2bf(f2.y) << 16);
        p1.y = f2bf(f2.z) | ((u32)f2bf(f2.w) << 16);
        p1.z = f2bf(f3.x) | ((u32)f2bf(f3.y) << 16);
        p1.w = f2bf(f3.z) | ((u32)f2bf(f3.w) << 16);
        u16* dp = &sm.g.Alds[r][kc];
        *(uint4*)dp = p0;
        *(uint4*)(dp + 8) = p1;
      }
      // stage W^T: 128 rows x 128 k, straight bf16 copy. thread: n=tid>>1, kc2=(tid&1)*64
      {
        const int n = tid >> 1, kc2 = (tid & 1) * 64;
        const uint4* sp = (const uint4*)(WbT + (size_t)n * IN_F + s * KH + kc2);
        uint4* dp = (uint4*)&sm.g.Wlds[n][kc2];
        #pragma unroll
        for (int q = 0; q < 8; ++q) dp[q] = sp[q];
      }
      __syncthreads();
      #pragma unroll
      for (int ks = 0; ks < KH / 32; ++ks) {          // 4 MFMA K-steps per half
        const int k0 = ks * 32 + kg * 8;
        bf16x8 af0 = *(const bf16x8*)&sm.g.Alds[r15][k0];
        bf16x8 af1 = *(const bf16x8*)&sm.g.Alds[16 + r15][k0];
        bf16x8 bf0 = *(const bf16x8*)&sm.g.Wlds[(2 * w + 0) * 16 + r15][k0];
        bf16x8 bf1 = *(const bf16x8*)&sm.g.Wlds[(2 * w + 1) * 16 + r15][k0];
        acc[0][0] = __builtin_amdgcn_mfma_f32_16x16x32_bf16(af0, bf0, acc[0][0], 0, 0, 0);
        acc[0][1] = __builtin_amdgcn_mfma_f32_16x16x32_bf16(af0, bf1, acc[0][1], 0, 0, 0);
        acc[1][0] = __builtin_amdgcn_mfma_f32_16x16x32_bf16(af1, bf0, acc[1][0], 0, 0, 0);
        acc[1][1] = __builtin_amdgcn_mfma_f32_16x16x32_bf16(af1, bf1, acc[1][1], 0, 0, 0);
      }
      __syncthreads();
    }
    // epilogue: Whb bf16 store + fused Wh1/Wh2 (f32 acc; C/D: col=lane&15, row=kg*4+reg)
    float a1v[2], a2v[2];
    #pragma unroll
    for (int t = 0; t < 2; ++t) {
      const int col = (2 * w + t) * 16 + r15;
      a1v[t] = a[col];
      a2v[t] = a[OUT_F + col];
    }
    #pragma unroll
    for (int m = 0; m < 2; ++m) {
      float pr1[4] = {0.f, 0.f, 0.f, 0.f}, pr2[4] = {0.f, 0.f, 0.f, 0.f};
      #pragma unroll
      for (int t = 0; t < 2; ++t) {
        const int col = (2 * w + t) * 16 + r15;
        #pragma unroll
        for (int r = 0; r < 4; ++r) {
          const float v = acc[m][t][r];
          Whb[((size_t)(row0 + m * 16 + kg * 4 + r) << 7) + col] = f2bf(v);
          pr1[r] = fmaf(v, a1v[t], pr1[r]);
          pr2[r] = fmaf(v, a2v[t], pr2[r]);
        }
      }
      #pragma unroll
      for (int off = 8; off >= 1; off >>= 1) {        // reduce over the 16 cols (r15)
        #pragma unroll
        for (int r = 0; r < 4; ++r) {
          pr1[r] += __shfl_xor(pr1[r], off);
          pr2[r] += __shfl_xor(pr2[r], off);
        }
      }
      if (r15 == 0) {
        #pragma unroll
        for (int r = 0; r < 4; ++r) {
          atomicAdd(&sm.g.whp[0][m * 16 + kg * 4 + r], pr1[r]);
          atomicAdd(&sm.g.whp[1][m * 16 + kg * 4 + r], pr2[r]);
        }
      }
    }
    __syncthreads();
    if (tid < BM) {
      Wh1[row0 + tid] = sm.g.whp[0][tid];
      Wh2[row0 + tid] = sm.g.whp[1][tid];
    }
  } else {
    // ---------------- edge binning ----------------
    if (tid < EDGE_F) {
      float s = 0.f;
      #pragma unroll
      for (int j = 0; j < EDGE_F; ++j) s += W_edge[tid * EDGE_F + j] * a[2 * OUT_F + j];
      sm.wc[tid] = s;
    }
    __syncthreads();
    float wcr[EDGE_F];
    #pragma unroll
    for (int j = 0; j < EDGE_F; ++j) wcr[j] = sm.wc[j];
    for (int k = (b - GEMM_NB) * 256 + tid; k < N_EDGES; k += EDGE_NB * 256) {
      const float4* r4 = (const float4*)(ef + (size_t)k * EDGE_F);
      float4 v0 = r4[0], v1 = r4[1], v2 = r4[2], v3 = r4[3];
      float sv = v0.x*wcr[0] + v0.y*wcr[1] + v0.z*wcr[2]  + v0.w*wcr[3]
               + v1.x*wcr[4] + v1.y*wcr[5] + v1.z*wcr[6]  + v1.w*wcr[7]
               + v2.x*wcr[8] + v2.y*wcr[9] + v2.z*wcr[10] + v2.w*wcr[11]
               + v3.x*wcr[12]+ v3.y*wcr[13]+ v3.z*wcr[14] + v3.w*wcr[15];
      int s = src[k], d = dst[k];
      int pos = atomicAdd(&counts[s], 1);     // counts zeroed by init_k
      if (pos < CAPB) bins[(size_t)s * CAPB + pos] = make_int2(d, __float_as_int(sv));
    }
  }
}

// ---------------- phase 2: attention, one wave per row (verbatim from R9, passed) ----------------
__global__ __launch_bounds__(256) void phase2_k(
    const u16* __restrict__ Whb, const float* __restrict__ Wh1, const float* __restrict__ Wh2,
    const int* __restrict__ counts, const int2* __restrict__ bins, float* __restrict__ out)
{
  __shared__ int   sdst[4][CAPB + 8];
  __shared__ float sval[4][CAPB];
  __shared__ float sw[4][CAPB + 8];
  const int wsl  = threadIdx.x >> 6;
  const int lane = threadIdx.x & 63;
  const int row  = blockIdx.x * 4 + wsl;
  int len = counts[row];
  len = len < CAPB ? len : CAPB;
  const int2* bp = bins + (size_t)row * CAPB;
  for (int t = lane; t < len; t += 64) {      // wave-private LDS slice: no block barrier
    int2 e = bp[t];
    sdst[wsl][t] = e.x;
    sval[wsl][t] = __int_as_float(e.y);
  }
  const float wh1 = Wh1[row];
  float e_loc[CAPB / 64];
  float lmax = -INFINITY;
  int diag_loc = 0;
  #pragma unroll
  for (int u = 0; u < CAPB / 64; ++u) {
    int t = lane + 64 * u;
    float ev = -INFINITY;                     // dup / out-of-range marker
    if (t < len) {
      int d = sdst[wsl][t];
      if (d == row) diag_loc = 1;
      bool first = true; float S = 0.f;
      for (int s2 = 0; s2 < len; ++s2) {      // O(len^2)/wave dedupe, len~33
        int d2 = sdst[wsl][s2];
        if (d2 == d) {
          if (s2 < t) { first = false; break; }
          S += sval[wsl][s2];                 // sum duplicates (JAX .add semantics)
        }
      }
      if (first) {
        float x = wh1 + Wh2[d] + S;
        ev = (x > 0.f) ? x : ALPHA_S * x;     // LeakyReLU
      }
    }
    e_loc[u] = ev;
    lmax = fmaxf(lmax, ev);
  }
  const bool has_diag = (__ballot(diag_loc) != 0ull);
  float e_diag = 0.f;
  if (!has_diag) {                            // adj diagonal forced on, no scatter term
    float x = wh1 + Wh2[row];
    e_diag = (x > 0.f) ? x : ALPHA_S * x;
    lmax = fmaxf(lmax, e_diag);
  }
  #pragma unroll
  for (int off = 32; off >= 1; off >>= 1) lmax = fmaxf(lmax, __shfl_xor(lmax, off));
  float lsum = 0.f;
  #pragma unroll
  for (int u = 0; u < CAPB / 64; ++u) {
    int t = lane + 64 * u;
    if (t < len) {
      float w = __expf(e_loc[u] - lmax);      // exp(-inf - m) = 0 for dup slots
      sw[wsl][t] = w;
      lsum += w;
    }
  }
  int lenB = len;
  if (!has_diag) {                            // append synthetic diag entry
    float wd = __expf(e_diag - lmax);
    if (lane == 0) { sdst[wsl][len] = row; sw[wsl][len] = wd; lsum += wd; }
    lenB = len + 1;
  }
  #pragma unroll
  for (int off = 32; off >= 1; off >>= 1) lsum += __shfl_xor(lsum, off);
  const int len4 = (lenB + 3) & ~3;           // pad for branch-free unroll-4
  {
    int t = lenB + lane;
    if (t < len4) { sdst[wsl][t] = row; sw[wsl][t] = 0.f; }
  }
  // Phase B: lane owns dims {2*lane, 2*lane+1}; one 4B bf16x2 gather per entry
  float acc0 = 0.f, acc1 = 0.f;
  for (int t = 0; t < len4; t += 4) {
    #pragma unroll
    for (int q = 0; q < 4; ++q) {
      float w = sw[wsl][t + q];               // LDS broadcast
      u32 v = *(const u32*)(Whb + ((size_t)sdst[wsl][t + q] << 7) + 2 * lane);
      acc0 = fmaf(w, __uint_as_float((v & 0xffffu) << 16), acc0);
      acc1 = fmaf(w, __uint_as_float(v & 0xffff0000u), acc1);
    }
  }
  const float inv = 1.f / lsum;
  float o0 = acc0 * inv, o1 = acc1 * inv;
  o0 = (o0 > 0.f) ? o0 : (__expf(o0) - 1.f);  // ELU
  o1 = (o1 > 0.f) ? o1 : (__expf(o1) - 1.f);
  *(float2*)(out + (size_t)row * OUT_F + 2 * lane) = make_float2(o0, o1);
}

extern "C" void kernel_launch(void* const* d_in, const int* in_sizes, int n_in,
                              void* d_out, int out_size, void* d_ws, size_t ws_size,
                              hipStream_t stream) {
  const float* h    = (const float*)d_in[0];
  const float* ef   = (const float*)d_in[1];
  const int*   eidx = (const int*)  d_in[2];
  // d_in[3] = adj — structurally redundant (edges + diagonal), never read: saves 256 MB
  const float* W    = (const float*)d_in[4];
  const float* Wedg = (const float*)d_in[5];
  const float* a    = (const float*)d_in[6];
  float* outp = (float*)d_out;

  char* wsp = (char*)d_ws;
  size_t off = 0;
  auto take = [&](size_t bytes) -> void* {
    void* p = wsp + off;
    off = (off + bytes + 255) & ~(size_t)255;
    return p;
  };
  int*   counts = (int*)  take((size_t)N_NODES * sizeof(int));             // 32 KiB
  u16*   WbT    = (u16*)  take((size_t)OUT_F * IN_F * sizeof(u16));        // 64 KiB
  u16*   Whb    = (u16*)  take((size_t)N_NODES * OUT_F * sizeof(u16));     // 2 MiB
  float* Wh1    = (float*)take((size_t)N_NODES * sizeof(float));
  float* Wh2    = (float*)take((size_t)N_NODES * sizeof(float));
  int2*  bins   = (int2*) take((size_t)N_NODES * CAPB * sizeof(int2));     // 8 MiB
  (void)ws_size; (void)in_sizes; (void)n_in; (void)out_size;

  const int* src = eidx;             // edge_indices[0, :]
  const int* dst = eidx + N_EDGES;   // edge_indices[1, :]

  hipLaunchKernelGGL(init_k,   dim3(128),          dim3(256), 0, stream, W, WbT, counts);
  hipLaunchKernelGGL(phase1_k, dim3(P1_NB),        dim3(256), 0, stream,
                     h, ef, src, dst, WbT, Wedg, a, Whb, Wh1, Wh2, counts, bins);
  hipLaunchKernelGGL(phase2_k, dim3(N_NODES / 4),  dim3(256), 0, stream,
                     Whb, Wh1, Wh2, counts, bins, outp);
}